// Round 8
// baseline (632.542 us; speedup 1.0000x reference)
//
#include <hip/hip_runtime.h>
#include <hip/hip_bf16.h>
#include <math.h>

typedef unsigned short u16;
typedef unsigned int u32;
using f32x4 = __attribute__((ext_vector_type(4))) float;
using short8 = __attribute__((ext_vector_type(8))) short;

#define LOGIT_MAX 4.605170185988091f
#define MFMA16(a,b,c) __builtin_amdgcn_mfma_f32_16x16x32_bf16((a),(b),(c),0,0,0)
// LDS XOR swizzles for 128B rows (m214: byte ^= ((row&7)<<4))
#define SWZK(r) ((((r)&7))<<4)
#define SWZV(r) (((((r)^((r)>>3))&7))<<4)
#define MCLOB asm volatile("" ::: "memory")

__device__ __forceinline__ u16 f2bf(float f) {
  u32 u = __float_as_uint(f);
  return (u16)((u + 0x7FFFu + ((u >> 16) & 1u)) >> 16);  // RNE
}
__device__ __forceinline__ u32 cvt_pk_bf16(float a, float b) {  // low=bf16(a), high=bf16(b)
  u32 r;
  asm("v_cvt_pk_bf16_f32 %0, %1, %2" : "=v"(r) : "v"(a), "v"(b));
  return r;
}
__device__ __forceinline__ void gload16(const void* g, void* l) {
  __builtin_amdgcn_global_load_lds(
      (const __attribute__((address_space(1))) u32*)g,
      (__attribute__((address_space(3))) u32*)l, 16, 0, 0);
}

// ------- fused f32->bf16 casts (5 regions) + padding-mask->bitmask -------
__global__ __launch_bounds__(256) void cast_all(
    const float* __restrict__ q, const float* __restrict__ kv,
    const float* __restrict__ Wq, const float* __restrict__ Wkv,
    const float* __restrict__ Wo, const int* __restrict__ pm,
    u16* __restrict__ qb, u16* __restrict__ kvb, u16* __restrict__ wqb,
    u16* __restrict__ wkvb, u16* __restrict__ wob, u32* __restrict__ mbits) {
  const int bid = blockIdx.x, t = threadIdx.x;
  if (bid == 5120) {  // mask -> bits: [2][2048] int -> [2][64] u32
    if (t < 128) {
      u32 bits = 0;
      const int* mp = pm + (t >> 6) * 2048 + (t & 63) * 32;
      #pragma unroll
      for (int j = 0; j < 32; ++j) bits |= (mp[j] ? 1u : 0u) << j;
      mbits[t] = bits;
    }
    return;
  }
  const float* s; u16* d; int base;
  if (bid < 1024)      { s = q;   d = qb;   base = bid; }
  else if (bid < 3072) { s = kv;  d = kvb;  base = bid - 1024; }
  else if (bid < 3584) { s = Wq;  d = wqb;  base = bid - 3072; }
  else if (bid < 4608) { s = Wkv; d = wkvb; base = bid - 3584; }
  else                 { s = Wo;  d = wob;  base = bid - 4608; }
  const size_t i = ((size_t)base * 256 + t) * 8;
  float4 a = *(const float4*)(s + i);
  float4 b = *(const float4*)(s + i + 4);
  short8 v;
  v[0] = (short)f2bf(a.x); v[1] = (short)f2bf(a.y);
  v[2] = (short)f2bf(a.z); v[3] = (short)f2bf(a.w);
  v[4] = (short)f2bf(b.x); v[5] = (short)f2bf(b.y);
  v[6] = (short)f2bf(b.z); v[7] = (short)f2bf(b.w);
  *(short8*)(d + i) = v;
}

// ------------- GEMM NT bf16 body: C[M,N] = A[M,K] * B[N,K]^T -------------
template<int BN, int NORM, bool BIAS, bool BF16OUT>
__device__ __forceinline__ void gemm_body(
    const u16* __restrict__ A, const u16* __restrict__ B,
    const float* __restrict__ bias, const float* __restrict__ ls,
    void* __restrict__ Cv, int M, int N, int K, int bx, int by,
    u16* a_s, u16* b_s)   // a_s[2][128*32], b_s[2][BN*32]
{
  constexpr int MT = (BN == 128) ? 4 : 2;
  constexpr int BSTR = BN * 32;
  const int t = threadIdx.x, w = t >> 6, l = t & 63, lo = l & 15, g = (l >> 4) & 3;
  const int row0 = by * 128, col0 = bx * BN;
  const int wr = (BN == 128) ? ((w >> 1) * 64) : (w * 32);
  const int wc = (BN == 128) ? ((w & 1) * 64) : 0;
  f32x4 acc[MT][4];
  #pragma unroll
  for (int i = 0; i < MT; ++i)
    #pragma unroll
    for (int j = 0; j < 4; ++j) { acc[i][j][0]=0.f; acc[i][j][1]=0.f; acc[i][j][2]=0.f; acc[i][j][3]=0.f; }

  const int sr = l >> 2, sc = (l & 3) * 8;
  const u16* Ag = A + (size_t)(row0 + w * 32 + sr) * K + sc;
  u16* adst = a_s + w * 1024;
  const u16* Bg;
  u16* bdst;
  if (BN == 128) { Bg = B + (size_t)(col0 + w * 32 + sr) * K + sc; bdst = b_s + w * 1024; }
  else           { Bg = B + (size_t)(col0 + w * 16 + sr) * K + sc; bdst = b_s + w * 512; }

  auto STAGE = [&](int kt, int pb) {
    const int k0 = kt * 32;
    gload16(Ag + k0, adst + pb * 4096);
    gload16(Ag + (size_t)16 * K + k0, adst + pb * 4096 + 512);
    gload16(Bg + k0, bdst + pb * BSTR);
    if (BN == 128) gload16(Bg + (size_t)16 * K + k0, bdst + pb * BSTR + 512);
  };

  const int NKT = K >> 5;
  STAGE(0, 0);
  for (int kt = 0; kt < NKT; ++kt) {
    const int cb = kt & 1;
    if (kt + 1 < NKT) {
      STAGE(kt + 1, cb ^ 1);
      MCLOB;
      if constexpr (BN == 128) asm volatile("s_waitcnt vmcnt(4)" ::: "memory");
      else                     asm volatile("s_waitcnt vmcnt(3)" ::: "memory");
    } else {
      asm volatile("s_waitcnt vmcnt(0)" ::: "memory");
    }
    __builtin_amdgcn_s_barrier();
    MCLOB;
    const u16* ab = a_s + cb * 4096;
    const u16* bb = b_s + cb * BSTR;
    short8 af[MT], bfr[4];
    #pragma unroll
    for (int mt = 0; mt < MT; ++mt) af[mt] = *(const short8*)&ab[(wr + mt * 16 + lo) * 32 + g * 8];
    #pragma unroll
    for (int nt = 0; nt < 4; ++nt) bfr[nt] = *(const short8*)&bb[(wc + nt * 16 + lo) * 32 + g * 8];
    #pragma unroll
    for (int mt = 0; mt < MT; ++mt)
      #pragma unroll
      for (int nt = 0; nt < 4; ++nt)
        acc[mt][nt] = MFMA16(af[mt], bfr[nt], acc[mt][nt]);
    MCLOB;
    __builtin_amdgcn_s_barrier();
  }
  if (NORM == 2 || (NORM == 1 && col0 < 1024)) {
    float scl = 1.f;
    if (NORM == 2) scl = __expf(fminf(ls[(col0 + wc) >> 6], LOGIT_MAX));
    #pragma unroll
    for (int mt = 0; mt < MT; ++mt)
      #pragma unroll
      for (int r = 0; r < 4; ++r) {
        float s = 0.f;
        #pragma unroll
        for (int nt = 0; nt < 4; ++nt) s = fmaf(acc[mt][nt][r], acc[mt][nt][r], s);
        s += __shfl_xor(s, 1); s += __shfl_xor(s, 2);
        s += __shfl_xor(s, 4); s += __shfl_xor(s, 8);
        float inv = scl / fmaxf(sqrtf(s), 1e-12f);
        #pragma unroll
        for (int nt = 0; nt < 4; ++nt) acc[mt][nt][r] *= inv;
      }
  }
  #pragma unroll
  for (int mt = 0; mt < MT; ++mt) {
    const int rrow = row0 + wr + mt * 16 + g * 4;
    #pragma unroll
    for (int nt = 0; nt < 4; ++nt) {
      const int ccol = col0 + wc + nt * 16 + lo;
      const float bv = BIAS ? bias[ccol] : 0.f;
      #pragma unroll
      for (int r = 0; r < 4; ++r) {
        const float v = acc[mt][nt][r] + bv;
        if (BF16OUT) ((u16*)Cv)[(size_t)(rrow + r) * N + ccol] = f2bf(v);
        else         ((float*)Cv)[(size_t)(rrow + r) * N + ccol] = v;
      }
    }
  }
}

__global__ __launch_bounds__(256) void proj_fused(
    const u16* __restrict__ q_bf, const u16* __restrict__ kv_bf,
    const u16* __restrict__ Wq_bf, const u16* __restrict__ Wkv_bf,
    const float* __restrict__ ls, u16* __restrict__ qh, u16* __restrict__ kvp) {
  __shared__ __align__(16) u16 a_s[2 * 4096];
  __shared__ __align__(16) u16 b_s[2 * 4096];
  const int bid = blockIdx.x;
  if (bid < 512)
    gemm_body<128, 1, false, true>(kv_bf, Wkv_bf, nullptr, nullptr, kvp,
                                   4096, 2048, 1024, bid & 15, bid >> 4, a_s, b_s);
  else
    gemm_body<128, 2, false, true>(q_bf, Wq_bf, nullptr, ls, qh,
                                   2048, 1024, 1024, (bid - 512) & 7, (bid - 512) >> 3, a_s, b_s);
}

__global__ __launch_bounds__(256) void gemm_out(
    const u16* __restrict__ xb, const u16* __restrict__ Wo_bf,
    const float* __restrict__ bo, float* __restrict__ out) {
  __shared__ __align__(16) u16 a_s[2 * 4096];
  __shared__ __align__(16) u16 b_s[2 * 2048];
  gemm_body<64, 0, true, false>(xb, Wo_bf, bo, nullptr, out,
                                2048, 1024, 1024, blockIdx.x & 15, blockIdx.x >> 4, a_s, b_s);
}

// ---------------- Flash attention, bf16 MFMA, QBLK=64, KVBLK=64, 4 waves ----------------
// ALIBI=1: real kernel. ALIBI=0: diagnostic (alibi=0, REP internal repeats).
template<int ALIBI, int REP>
__global__ __launch_bounds__(256) void attn_mfma(
    const u16* __restrict__ qn, const u16* __restrict__ kvp,
    const float* __restrict__ alibi, const u32* __restrict__ mbits,
    u16* __restrict__ xb)
{
  __shared__ __align__(16) u16 k_s[2][64 * 64];
  __shared__ __align__(16) u16 vT_s[2][64 * 64];
  __shared__ __align__(16) u16 p_s[4][16 * 64];
  const int t = threadIdx.x, w = t >> 6, l = t & 63, lo = l & 15, g = (l >> 4) & 3;
  const int bid = blockIdx.x;
  const int bh = bid & 31, b = bh >> 4, h = bh & 15;
  const int n0 = (bid >> 5) * 64;

  const u16* qrow = qn + (size_t)(b * 1024 + n0 + w * 16 + lo) * 1024 + h * 64;
  const short8 qf0 = *(const short8*)(qrow + g * 8);
  const short8 qf1 = *(const short8*)(qrow + 32 + g * 8);

  const u16* kbase = kvp + (size_t)(b * 2048) * 2048 + h * 64;
  const u16* vbase = kbase + 1024;
  const float* albase = alibi + ((size_t)(bh * 1024 + n0 + w * 16 + lo)) * 2048;

  const int kr0 = w * 16 + (l >> 3);
  const int kcolb = (l & 7) * 16;
  const int vdq = (t & 7) * 8;
  const int vmp = (t >> 3) * 2;

  float mrow = -1e30f, lrow = 0.f;
  f32x4 oa[4];
  #pragma unroll
  for (int d = 0; d < 4; ++d) { oa[d][0]=0.f; oa[d][1]=0.f; oa[d][2]=0.f; oa[d][3]=0.f; }

  float4 alr[16];
  short8 va, vb;
  const u32 mword = mbits[b * 64 + l];

#define ALOAD(G) {                                                                  \
    const float* abp = albase + (size_t)(G) * 256;                                  \
    _Pragma("unroll")                                                               \
    for (int jj = 0; jj < 16; ++jj)                                                 \
      alr[jj] = *(const float4*)(abp + (jj >> 2) * 64 + (jj & 3) * 16 + g * 4);     \
  }

#define BODY(J, CB, TI) {                                                           \
    { char* vdst = (char*)vT_s[CB];                                                 \
      _Pragma("unroll")                                                             \
      for (int j = 0; j < 8; ++j) {                                                 \
        u32 pk = (u32)(u16)va[j] | ((u32)(u16)vb[j] << 16);                         \
        int r = vdq + j;                                                            \
        *(u32*)(vdst + r * 128 + ((vmp * 2) ^ SWZV(r))) = pk; } }                   \
    MCLOB;                                                                          \
    if ((TI) < 31) {                                                                \
      const int m1 = ((TI) + 1) * 64;                                               \
      gload16((const char*)kbase + (size_t)(m1 + kr0) * 4096 + (kcolb ^ SWZK(kr0)), \
              (char*)k_s[(CB) ^ 1] + w * 2048);                                     \
      gload16((const char*)kbase + (size_t)(m1 + kr0 + 8) * 4096 + (kcolb ^ SWZK(kr0 + 8)), \
              (char*)k_s[(CB) ^ 1] + w * 2048 + 1024);                              \
      MCLOB;                                                                        \
      const u16* v1p = vbase + (size_t)(m1 + vmp) * 2048 + vdq;                     \
      va = *(const short8*)v1p;                                                     \
      vb = *(const short8*)(v1p + 2048);                                            \
    }                                                                               \
    asm volatile("s_waitcnt lgkmcnt(0)" ::: "memory");                              \
    __builtin_amdgcn_s_barrier();                                                   \
    MCLOB;                                                                          \
    {                                                                               \
      f32x4 st[4];                                                                  \
      _Pragma("unroll")                                                             \
      for (int mt = 0; mt < 4; ++mt) {                                              \
        const int r = mt * 16 + lo;                                                 \
        const char* krow = (const char*)k_s[CB] + r * 128;                          \
        short8 ka0 = *(const short8*)(krow + ((g * 16) ^ SWZK(r)));                 \
        short8 ka1 = *(const short8*)(krow + ((64 + g * 16) ^ SWZK(r)));            \
        f32x4 z; z[0]=0.f; z[1]=0.f; z[2]=0.f; z[3]=0.f;                            \
        st[mt] = MFMA16(ka0, qf0, z);                                               \
        st[mt] = MFMA16(ka1, qf1, st[mt]);                                          \
      }                                                                             \
      const u32 cw0 = __shfl(mword, (TI) * 2), cw1 = __shfl(mword, (TI) * 2 + 1);   \
      float p[16]; float pmax = -1e30f;                                             \
      _Pragma("unroll")                                                             \
      for (int mt = 0; mt < 4; ++mt) {                                              \
        const float4 A4 = alr[(J) * 4 + mt];                                        \
        const float aa[4] = {A4.x, A4.y, A4.z, A4.w};                               \
        const u32 wsel = (mt >= 2) ? cw1 : cw0;                                     \
        _Pragma("unroll")                                                           \
        for (int r = 0; r < 4; ++r) {                                               \
          const int idx = mt * 16 + g * 4 + r;                                      \
          const float v = ((wsel >> (idx & 31)) & 1u) ? -1e30f : (st[mt][r] + aa[r]); \
          p[mt * 4 + r] = v;                                                        \
          pmax = fmaxf(pmax, v);                                                    \
        }                                                                           \
      }                                                                             \
      pmax = fmaxf(pmax, __shfl_xor(pmax, 16));                                     \
      pmax = fmaxf(pmax, __shfl_xor(pmax, 32));                                     \
      const float mnew = fmaxf(mrow, pmax);                                         \
      const float f = __expf(mrow - mnew);                                          \
      float sum = 0.f;                                                              \
      _Pragma("unroll")                                                             \
      for (int i = 0; i < 16; ++i) { p[i] = __expf(p[i] - mnew); sum += p[i]; }     \
      sum += __shfl_xor(sum, 16);                                                   \
      sum += __shfl_xor(sum, 32);                                                   \
      lrow = lrow * f + sum;                                                        \
      mrow = mnew;                                                                  \
      if (ALIBI && (J) == 3 && g4 < 7) ALOAD(g4 + 1);                               \
      char* pwB = (char*)p_s[w];                                                    \
      _Pragma("unroll")                                                             \
      for (int mt = 0; mt < 4; ++mt) {                                              \
        uint2 uu;                                                                   \
        uu.x = cvt_pk_bf16(p[mt * 4 + 0], p[mt * 4 + 1]);                           \
        uu.y = cvt_pk_bf16(p[mt * 4 + 2], p[mt * 4 + 3]);                           \
        *(uint2*)(pwB + lo * 128 + ((mt * 32 + g * 8) ^ SWZK(lo))) = uu;            \
      }                                                                             \
      asm volatile("" ::: "memory");                                                \
      const float f0 = __shfl(f, 4 * g + 0), f1 = __shfl(f, 4 * g + 1);             \
      const float f2v = __shfl(f, 4 * g + 2), f3 = __shfl(f, 4 * g + 3);            \
      f32x4 fv; fv[0] = f0; fv[1] = f1; fv[2] = f2v; fv[3] = f3;                    \
      _Pragma("unroll")                                                             \
      for (int d = 0; d < 4; ++d) oa[d] *= fv;                                      \
      _Pragma("unroll")                                                             \
      for (int kt = 0; kt < 2; ++kt) {                                              \
        short8 pa = *(const short8*)(pwB + lo * 128 + ((kt * 64 + g * 16) ^ SWZK(lo))); \
        _Pragma("unroll")                                                           \
        for (int d = 0; d < 4; ++d) {                                               \
          const int r = d * 16 + lo;                                                \
          short8 vf = *(const short8*)((const char*)vT_s[CB] + r * 128 + ((kt * 64 + g * 16) ^ SWZV(r))); \
          oa[d] = MFMA16(pa, vf, oa[d]);                                            \
        }                                                                           \
      }                                                                             \
    }                                                                               \
    MCLOB;                                                                          \
    __builtin_amdgcn_s_barrier();                                                   \
  }

  for (int rep = 0; rep < REP; ++rep) {
    mrow = -1e30f; lrow = 0.f;
    // prologue (per rep): alibi group 0, K(0), V(0)
    if constexpr (ALIBI) { ALOAD(0); }
    else {
      #pragma unroll
      for (int jj = 0; jj < 16; ++jj) { alr[jj].x=0.f; alr[jj].y=0.f; alr[jj].z=0.f; alr[jj].w=0.f; }
    }
    MCLOB;
    gload16((const char*)kbase + (size_t)kr0 * 4096 + (kcolb ^ SWZK(kr0)), (char*)k_s[0] + w * 2048);
    gload16((const char*)kbase + (size_t)(kr0 + 8) * 4096 + (kcolb ^ SWZK(kr0 + 8)), (char*)k_s[0] + w * 2048 + 1024);
    MCLOB;
    {
      const u16* v0p = vbase + (size_t)vmp * 2048 + vdq;
      va = *(const short8*)v0p;
      vb = *(const short8*)(v0p + 2048);
    }
    MCLOB;

    for (int g4 = 0; g4 < 8; ++g4) {
      const int t0 = g4 * 4;
      if constexpr (ALIBI) {
        if (g4 == 0) asm volatile("s_waitcnt vmcnt(2)" ::: "memory");
        else         asm volatile("s_waitcnt vmcnt(18)" ::: "memory");
      } else {
        asm volatile("s_waitcnt vmcnt(2)" ::: "memory");
      }
      BODY(0, 0, t0 + 0);
      asm volatile("s_waitcnt vmcnt(2)" ::: "memory");
      BODY(1, 1, t0 + 1);
      asm volatile("s_waitcnt vmcnt(2)" ::: "memory");
      BODY(2, 0, t0 + 2);
      asm volatile("s_waitcnt vmcnt(2)" ::: "memory");
      BODY(3, 1, t0 + 3);
    }
    if (rep + 1 < REP) {
      asm volatile("s_waitcnt vmcnt(0) lgkmcnt(0)" ::: "memory");
      __syncthreads();
    }
  }
#undef BODY
#undef ALOAD

  const float l0 = __shfl(lrow, 4 * g + 0), l1 = __shfl(lrow, 4 * g + 1);
  const float l2 = __shfl(lrow, 4 * g + 2), l3 = __shfl(lrow, 4 * g + 3);
  const float iv[4] = {1.f / l0, 1.f / l1, 1.f / l2, 1.f / l3};
  u16* xrow = xb + (size_t)(b * 1024 + n0 + w * 16) * 1024 + h * 64;
  #pragma unroll
  for (int d = 0; d < 4; ++d)
    #pragma unroll
    for (int r = 0; r < 4; ++r)
      xrow[(size_t)(4 * g + r) * 1024 + d * 16 + lo] = f2bf(oa[d][r] * iv[r]);
}

// ---- PROBE A: attn's alibi pattern, free-running (max outstanding), REP=3 ----
__global__ __launch_bounds__(256) void probe_alibi_a(const float* __restrict__ alibi,
                                                     float* __restrict__ o) {
  const int t = threadIdx.x, w = t >> 6, l = t & 63, g = (l >> 4) & 3;
  const int lo = l & 15;
  float4 s; s.x = 0.f; s.y = 0.f; s.z = 0.f; s.w = 0.f;
  for (int rep = 0; rep < 3; ++rep) {
    const int bidr = (blockIdx.x + rep * 257) & 511;   // shift per rep: defeat CSE
    const int bh = bidr & 31;
    const int n0 = (bidr >> 5) * 64;
    const float* albase = alibi + ((size_t)(bh * 1024 + n0 + w * 16 + lo)) * 2048;
    for (int g4 = 0; g4 < 8; ++g4) {
      const float* abp = albase + (size_t)g4 * 256;
      #pragma unroll
      for (int jj = 0; jj < 16; ++jj) {
        float4 v = *(const float4*)(abp + (jj >> 2) * 64 + (jj & 3) * 16 + g * 4);
        s.x += v.x; s.y += v.y; s.z += v.z; s.w += v.w;
      }
    }
  }
  o[(size_t)blockIdx.x * 256 + t] = s.x + s.y + s.z + s.w;
}

// ---- PROBE B: row-sequential pattern (block = 16 full 8KB rows), REP=4 ----
__global__ __launch_bounds__(256) void probe_alibi_b(const float* __restrict__ alibi,
                                                     float* __restrict__ o) {
  const int t = threadIdx.x, w = t >> 6, l = t & 63;
  float4 s; s.x = 0.f; s.y = 0.f; s.z = 0.f; s.w = 0.f;
  for (int rep = 0; rep < 4; ++rep) {
    const int bidr = (blockIdx.x + rep * 521) & 2047;
    const int row = bidr * 16 + w * 4 + (l >> 4);       // [B*H*N] = 32768 rows
    const float* rp = alibi + (size_t)row * 2048 + (l & 15) * 4;
    #pragma unroll
    for (int c = 0; c < 32; ++c) {
      float4 v = *(const float4*)(rp + c * 64);
      s.x += v.x; s.y += v.y; s.z += v.z; s.w += v.w;
    }
  }
  o[(size_t)(blockIdx.x & 511) * 256 + t] = s.x + s.y + s.z + s.w;
}

extern "C" void kernel_launch(void* const* d_in, const int* in_sizes, int n_in,
                              void* d_out, int out_size, void* d_ws, size_t ws_size,
                              hipStream_t stream) {
  const float* q     = (const float*)d_in[0];
  const float* kv    = (const float*)d_in[1];
  const int*   pmask = (const int*)d_in[2];
  const float* alibi = (const float*)d_in[3];
  const float* Wq    = (const float*)d_in[4];
  const float* Wkv   = (const float*)d_in[5];
  const float* Wo    = (const float*)d_in[6];
  const float* bo    = (const float*)d_in[7];
  const float* ls    = (const float*)d_in[8];
  float* out = (float*)d_out;

  u16* ws = (u16*)d_ws;
  u16* q_bf   = ws;
  u16* kv_bf  = ws + (size_t)2  * 1024 * 1024;
  u16* Wq_bf  = ws + (size_t)6  * 1024 * 1024;
  u16* Wkv_bf = ws + (size_t)7  * 1024 * 1024;
  u16* Wo_bf  = ws + (size_t)9  * 1024 * 1024;
  u16* qh_bf  = ws + (size_t)10 * 1024 * 1024;
  u16* kvp_bf = ws + (size_t)12 * 1024 * 1024;
  u16* xb     = ws + (size_t)20 * 1024 * 1024;
  u32* mbits  = (u32*)(ws + (size_t)22 * 1024 * 1024);
  float* ps   = (float*)(ws + (size_t)24 * 1024 * 1024);   // probe sums (512KB)
  u16* xb2    = ws + (size_t)26 * 1024 * 1024;             // probe attn output

  cast_all<<<5121, 256, 0, stream>>>(q, kv, Wq, Wkv, Wo, pmask,
                                     q_bf, kv_bf, Wq_bf, Wkv_bf, Wo_bf, mbits);

  proj_fused<<<640, 256, 0, stream>>>(q_bf, kv_bf, Wq_bf, Wkv_bf, ls, qh_bf, kvp_bf);

  attn_mfma<1, 1><<<512, 256, 0, stream>>>(qh_bf, kvp_bf, alibi, mbits, xb);

  gemm_out<<<256, 256, 0, stream>>>(xb, Wo_bf, bo, out);

  // ---- diagnostics (scratch only) ----
  probe_alibi_a<<<512, 256, 0, stream>>>(alibi, ps);
  probe_alibi_b<<<2048, 256, 0, stream>>>(alibi, ps);
  attn_mfma<0, 4><<<512, 256, 0, stream>>>(qh_bf, kvp_bf, alibi, mbits, xb2);
}

// Round 10
// 173.941 us; speedup vs baseline: 3.6365x; 3.6365x over previous
//
#include <hip/hip_runtime.h>
#include <hip/hip_bf16.h>
#include <math.h>

typedef unsigned short u16;
typedef unsigned int u32;
using f32x4 = __attribute__((ext_vector_type(4))) float;
using short8 = __attribute__((ext_vector_type(8))) short;

#define LOGIT_MAX 4.605170185988091f
#define MFMA16(a,b,c) __builtin_amdgcn_mfma_f32_16x16x32_bf16((a),(b),(c),0,0,0)
// LDS XOR swizzles (m214: byte ^= f(row)<<4), involutions applied to both sides
#define SWZK(r) ((((r)&7))<<4)
#define SWZV(r) (((((r)^((r)>>3))&7))<<4)
#define MCLOB asm volatile("" ::: "memory")
#define AT_SB __builtin_amdgcn_sched_barrier(0)

__device__ __forceinline__ u16 f2bf(float f) {
  u32 u = __float_as_uint(f);
  return (u16)((u + 0x7FFFu + ((u >> 16) & 1u)) >> 16);  // RNE
}
__device__ __forceinline__ u32 cvt_pk_bf16(float a, float b) {
  u32 r;
  asm("v_cvt_pk_bf16_f32 %0, %1, %2" : "=v"(r) : "v"(a), "v"(b));
  return r;
}
__device__ __forceinline__ void gload16(const void* g, void* l) {
  __builtin_amdgcn_global_load_lds(
      (const __attribute__((address_space(1))) u32*)g,
      (__attribute__((address_space(3))) u32*)l, 16, 0, 0);
}

// ------- fused f32->bf16 casts (5 regions) + padding-mask->bitmask -------
__global__ __launch_bounds__(256) void cast_all(
    const float* __restrict__ q, const float* __restrict__ kv,
    const float* __restrict__ Wq, const float* __restrict__ Wkv,
    const float* __restrict__ Wo, const int* __restrict__ pm,
    u16* __restrict__ qb, u16* __restrict__ kvb, u16* __restrict__ wqb,
    u16* __restrict__ wkvb, u16* __restrict__ wob, u32* __restrict__ mbits) {
  const int bid = blockIdx.x, t = threadIdx.x;
  if (bid == 5120) {
    if (t < 128) {
      u32 bits = 0;
      const int* mp = pm + (t >> 6) * 2048 + (t & 63) * 32;
      #pragma unroll
      for (int j = 0; j < 32; ++j) bits |= (mp[j] ? 1u : 0u) << j;
      mbits[t] = bits;
    }
    return;
  }
  const float* s; u16* d; int base;
  if (bid < 1024)      { s = q;   d = qb;   base = bid; }
  else if (bid < 3072) { s = kv;  d = kvb;  base = bid - 1024; }
  else if (bid < 3584) { s = Wq;  d = wqb;  base = bid - 3072; }
  else if (bid < 4608) { s = Wkv; d = wkvb; base = bid - 3584; }
  else                 { s = Wo;  d = wob;  base = bid - 4608; }
  const size_t i = ((size_t)base * 256 + t) * 8;
  float4 a = *(const float4*)(s + i);
  float4 b = *(const float4*)(s + i + 4);
  short8 v;
  v[0] = (short)f2bf(a.x); v[1] = (short)f2bf(a.y);
  v[2] = (short)f2bf(a.z); v[3] = (short)f2bf(a.w);
  v[4] = (short)f2bf(b.x); v[5] = (short)f2bf(b.y);
  v[6] = (short)f2bf(b.z); v[7] = (short)f2bf(b.w);
  *(short8*)(d + i) = v;
}

// ------------- GEMM NT bf16 body: C[M,N] = A[M,K] * B[N,K]^T -------------
template<int BN, int NORM, bool BIAS, bool BF16OUT>
__device__ __forceinline__ void gemm_body(
    const u16* __restrict__ A, const u16* __restrict__ B,
    const float* __restrict__ bias, const float* __restrict__ ls,
    void* __restrict__ Cv, int M, int N, int K, int bx, int by,
    u16* a_s, u16* b_s)
{
  constexpr int MT = (BN == 128) ? 4 : 2;
  constexpr int BSTR = BN * 32;
  const int t = threadIdx.x, w = t >> 6, l = t & 63, lo = l & 15, g = (l >> 4) & 3;
  const int row0 = by * 128, col0 = bx * BN;
  const int wr = (BN == 128) ? ((w >> 1) * 64) : (w * 32);
  const int wc = (BN == 128) ? ((w & 1) * 64) : 0;
  f32x4 acc[MT][4];
  #pragma unroll
  for (int i = 0; i < MT; ++i)
    #pragma unroll
    for (int j = 0; j < 4; ++j) { acc[i][j][0]=0.f; acc[i][j][1]=0.f; acc[i][j][2]=0.f; acc[i][j][3]=0.f; }

  const int sr = l >> 2, sc = (l & 3) * 8;
  const u16* Ag = A + (size_t)(row0 + w * 32 + sr) * K + sc;
  u16* adst = a_s + w * 1024;
  const u16* Bg;
  u16* bdst;
  if (BN == 128) { Bg = B + (size_t)(col0 + w * 32 + sr) * K + sc; bdst = b_s + w * 1024; }
  else           { Bg = B + (size_t)(col0 + w * 16 + sr) * K + sc; bdst = b_s + w * 512; }

  auto STAGE = [&](int kt, int pb) {
    const int k0 = kt * 32;
    gload16(Ag + k0, adst + pb * 4096);
    gload16(Ag + (size_t)16 * K + k0, adst + pb * 4096 + 512);
    gload16(Bg + k0, bdst + pb * BSTR);
    if (BN == 128) gload16(Bg + (size_t)16 * K + k0, bdst + pb * BSTR + 512);
  };

  const int NKT = K >> 5;
  STAGE(0, 0);
  for (int kt = 0; kt < NKT; ++kt) {
    const int cb = kt & 1;
    if (kt + 1 < NKT) {
      STAGE(kt + 1, cb ^ 1);
      MCLOB;
      if constexpr (BN == 128) asm volatile("s_waitcnt vmcnt(4)" ::: "memory");
      else                     asm volatile("s_waitcnt vmcnt(3)" ::: "memory");
    } else {
      asm volatile("s_waitcnt vmcnt(0)" ::: "memory");
    }
    __builtin_amdgcn_s_barrier();
    MCLOB;
    const u16* ab = a_s + cb * 4096;
    const u16* bb = b_s + cb * BSTR;
    short8 af[MT], bfr[4];
    #pragma unroll
    for (int mt = 0; mt < MT; ++mt) af[mt] = *(const short8*)&ab[(wr + mt * 16 + lo) * 32 + g * 8];
    #pragma unroll
    for (int nt = 0; nt < 4; ++nt) bfr[nt] = *(const short8*)&bb[(wc + nt * 16 + lo) * 32 + g * 8];
    #pragma unroll
    for (int mt = 0; mt < MT; ++mt)
      #pragma unroll
      for (int nt = 0; nt < 4; ++nt)
        acc[mt][nt] = MFMA16(af[mt], bfr[nt], acc[mt][nt]);
    MCLOB;
    __builtin_amdgcn_s_barrier();
  }
  if (NORM == 2 || (NORM == 1 && col0 < 1024)) {
    float scl = 1.f;
    if (NORM == 2) scl = __expf(fminf(ls[(col0 + wc) >> 6], LOGIT_MAX));
    #pragma unroll
    for (int mt = 0; mt < MT; ++mt)
      #pragma unroll
      for (int r = 0; r < 4; ++r) {
        float s = 0.f;
        #pragma unroll
        for (int nt = 0; nt < 4; ++nt) s = fmaf(acc[mt][nt][r], acc[mt][nt][r], s);
        s += __shfl_xor(s, 1); s += __shfl_xor(s, 2);
        s += __shfl_xor(s, 4); s += __shfl_xor(s, 8);
        float inv = scl / fmaxf(sqrtf(s), 1e-12f);
        #pragma unroll
        for (int nt = 0; nt < 4; ++nt) acc[mt][nt][r] *= inv;
      }
  }
  #pragma unroll
  for (int mt = 0; mt < MT; ++mt) {
    const int rrow = row0 + wr + mt * 16 + g * 4;
    #pragma unroll
    for (int nt = 0; nt < 4; ++nt) {
      const int ccol = col0 + wc + nt * 16 + lo;
      const float bv = BIAS ? bias[ccol] : 0.f;
      #pragma unroll
      for (int r = 0; r < 4; ++r) {
        const float v = acc[mt][nt][r] + bv;
        if (BF16OUT) ((u16*)Cv)[(size_t)(rrow + r) * N + ccol] = f2bf(v);
        else         ((float*)Cv)[(size_t)(rrow + r) * N + ccol] = v;
      }
    }
  }
}

__global__ __launch_bounds__(256) void proj_fused(
    const u16* __restrict__ q_bf, const u16* __restrict__ kv_bf,
    const u16* __restrict__ Wq_bf, const u16* __restrict__ Wkv_bf,
    const float* __restrict__ ls, u16* __restrict__ qh, u16* __restrict__ kvp) {
  __shared__ __align__(16) u16 a_s[2 * 4096];
  __shared__ __align__(16) u16 b_s[2 * 4096];
  const int bid = blockIdx.x;
  if (bid < 512)
    gemm_body<128, 1, false, true>(kv_bf, Wkv_bf, nullptr, nullptr, kvp,
                                   4096, 2048, 1024, bid & 15, bid >> 4, a_s, b_s);
  else
    gemm_body<128, 2, false, true>(q_bf, Wq_bf, nullptr, ls, qh,
                                   2048, 1024, 1024, (bid - 512) & 7, (bid - 512) >> 3, a_s, b_s);
}

__global__ __launch_bounds__(256) void gemm_out(
    const u16* __restrict__ xb, const u16* __restrict__ Wo_bf,
    const float* __restrict__ bo, float* __restrict__ out) {
  __shared__ __align__(16) u16 a_s[2 * 4096];
  __shared__ __align__(16) u16 b_s[2 * 2048];
  gemm_body<64, 0, true, false>(xb, Wo_bf, bo, nullptr, out,
                                2048, 1024, 1024, blockIdx.x & 15, blockIdx.x >> 4, a_s, b_s);
}

// ---------------- Flash attention, bf16 MFMA, QBLK=64, KVBLK=64, 4 waves ----------------
// R9 structure (alibi->LDS 3-buffer ring, 2-tile deadline, single-buffer V,
// counted vmcnt) + R7's proven sched_barrier(0) pinning at every staging/wait
// boundary (rule #18: "memory" clobber alone does not pin gload_lds/waitcnt order).
// LDS: K dbuf 16K + V 8K + P 8K + al 48K = 80KB (2 blocks/CU).
__global__ __launch_bounds__(256) void attn_mfma(
    const u16* __restrict__ qn, const u16* __restrict__ kvp,
    const float* __restrict__ alibi, const u32* __restrict__ mbits,
    u16* __restrict__ xb)
{
  __shared__ __align__(16) u16 k_s[2][64 * 64];      // 16 KB
  __shared__ __align__(16) u16 vT_s[64 * 64];        // 8 KB (single buffer)
  __shared__ __align__(16) u16 p_s[4][16 * 64];      // 8 KB
  __shared__ __align__(16) float al_s[3][64 * 64];   // 48 KB
  const int t = threadIdx.x, w = t >> 6, l = t & 63, lo = l & 15, g = (l >> 4) & 3;
  const int bid = blockIdx.x;
  const int bh = bid & 31, b = bh >> 4, h = bh & 15;
  const int n0 = (bid >> 5) * 64;

  const u16* qrow = qn + (size_t)(b * 1024 + n0 + w * 16 + lo) * 1024 + h * 64;
  const short8 qf0 = *(const short8*)(qrow + g * 8);
  const short8 qf1 = *(const short8*)(qrow + 32 + g * 8);

  const u16* kbase = kvp + (size_t)(b * 2048) * 2048 + h * 64;
  const u16* vbase = kbase + 1024;
  const float* arow = alibi + (size_t)(bh * 1024 + n0) * 2048;

  const int kr0 = w * 16 + (l >> 3);
  const int kcolb = (l & 7) * 16;
  const int vdq = (t & 7) * 8;
  const int vmp = (t >> 3) * 2;

  // alibi staging: gload i covers rows w*16+4i..+3; lane l -> row r=base+(l>>4),
  // source chunk pre-swizzled: (l&15)^(r&15)  (involution, undone on read)
  u32 aoff[4];
  #pragma unroll
  for (int i = 0; i < 4; ++i) {
    const int r = w * 16 + 4 * i + (l >> 4);
    aoff[i] = (u32)r * 2048u + (u32)(((l & 15) ^ (r & 15)) * 4);
  }
  const u32 mword = mbits[b * 64 + l];

  float mrow = -1e30f, lrow = 0.f;
  f32x4 oa[4];
  #pragma unroll
  for (int d = 0; d < 4; ++d) { oa[d][0]=0.f; oa[d][1]=0.f; oa[d][2]=0.f; oa[d][3]=0.f; }

  short8 va, vb;

#define ALSTAGE(M0, BUF) {                                                          \
    char* adb = (char*)al_s + (BUF) * 16384;                                        \
    _Pragma("unroll")                                                               \
    for (int i = 0; i < 4; ++i)                                                     \
      gload16(arow + aoff[i] + (M0), adb + (w * 16 + 4 * i) * 256);                 \
  }

  // ---- prologue: V(0), K(0), al(0)->buf0, al(1)->buf1 (order pinned) ----
  {
    const u16* v0p = vbase + (size_t)vmp * 2048 + vdq;
    va = *(const short8*)v0p;
    vb = *(const short8*)(v0p + 2048);
  }
  AT_SB;
  gload16((const char*)kbase + (size_t)kr0 * 4096 + (kcolb ^ SWZK(kr0)), (char*)k_s[0] + w * 2048);
  gload16((const char*)kbase + (size_t)(kr0 + 8) * 4096 + (kcolb ^ SWZK(kr0 + 8)), (char*)k_s[0] + w * 2048 + 1024);
  AT_SB;
  ALSTAGE(0, 0);
  AT_SB;
  ALSTAGE(64, 1);
  AT_SB;

  int acur = 0;
  for (int ti = 0; ti < 32; ++ti) {
    const int kb = ti & 1;
    // V write (consumes va/vb -> compiler auto-waits the V pair only)
    {
      char* vdst = (char*)vT_s;
      #pragma unroll
      for (int j = 0; j < 8; ++j) {
        u32 pk = (u32)(u16)va[j] | ((u32)(u16)vb[j] << 16);
        int r = vdq + j;
        *(u32*)(vdst + r * 128 + ((vmp * 2) ^ SWZV(r))) = pk;
      }
    }
    AT_SB;
    if (ti < 31) {  // V(t+1) regs, then K(t+1) gloads
      const int m1 = (ti + 1) * 64;
      const u16* v1p = vbase + (size_t)(m1 + vmp) * 2048 + vdq;
      va = *(const short8*)v1p;
      vb = *(const short8*)(v1p + 2048);
      AT_SB;
      gload16((const char*)kbase + (size_t)(m1 + kr0) * 4096 + (kcolb ^ SWZK(kr0)),
              (char*)k_s[kb ^ 1] + w * 2048);
      gload16((const char*)kbase + (size_t)(m1 + kr0 + 8) * 4096 + (kcolb ^ SWZK(kr0 + 8)),
              (char*)k_s[kb ^ 1] + w * 2048 + 1024);
    }
    AT_SB;
    if (ti < 30) {  // al(t+2) -> ring buffer (issued last: survives the vmcnt)
      const int awr = (acur == 0) ? 2 : acur - 1;   // (acur+2)%3
      ALSTAGE((ti + 2) * 64, awr);
    }
    AT_SB;
    if (ti < 30)       asm volatile("s_waitcnt vmcnt(12)" ::: "memory");
    else if (ti == 30) asm volatile("s_waitcnt vmcnt(8)" ::: "memory");
    else               asm volatile("s_waitcnt vmcnt(0)" ::: "memory");
    AT_SB;
    asm volatile("s_waitcnt lgkmcnt(0)" ::: "memory");
    AT_SB;
    __builtin_amdgcn_s_barrier();
    AT_SB;

    // ---- compute tile ti ----
    {
      f32x4 st[4];
      #pragma unroll
      for (int mt = 0; mt < 4; ++mt) {
        const int r = mt * 16 + lo;
        const char* krow = (const char*)k_s[kb] + r * 128;
        short8 ka0 = *(const short8*)(krow + ((g * 16) ^ SWZK(r)));
        short8 ka1 = *(const short8*)(krow + ((64 + g * 16) ^ SWZK(r)));
        f32x4 z; z[0]=0.f; z[1]=0.f; z[2]=0.f; z[3]=0.f;
        st[mt] = MFMA16(ka0, qf0, z);
        st[mt] = MFMA16(ka1, qf1, st[mt]);
      }
      const u32 cw0 = __shfl(mword, ti * 2), cw1 = __shfl(mword, ti * 2 + 1);
      const char* alb = (const char*)al_s + acur * 16384 + (w * 16 + lo) * 256;
      float p[16]; float pmax = -1e30f;
      #pragma unroll
      for (int mt = 0; mt < 4; ++mt) {
        const float4 A4 = *(const float4*)(alb + ((mt * 64 + g * 16) ^ (lo << 4)));
        const float aa[4] = {A4.x, A4.y, A4.z, A4.w};
        const u32 wsel = (mt >= 2) ? cw1 : cw0;
        #pragma unroll
        for (int r = 0; r < 4; ++r) {
          const int idx = mt * 16 + g * 4 + r;
          const float v = ((wsel >> (idx & 31)) & 1u) ? -1e30f : (st[mt][r] + aa[r]);
          p[mt * 4 + r] = v;
          pmax = fmaxf(pmax, v);
        }
      }
      pmax = fmaxf(pmax, __shfl_xor(pmax, 16));
      pmax = fmaxf(pmax, __shfl_xor(pmax, 32));
      const float mnew = fmaxf(mrow, pmax);
      const float f = __expf(mrow - mnew);
      float sum = 0.f;
      #pragma unroll
      for (int i = 0; i < 16; ++i) { p[i] = __expf(p[i] - mnew); sum += p[i]; }
      sum += __shfl_xor(sum, 16);
      sum += __shfl_xor(sum, 32);
      lrow = lrow * f + sum;
      mrow = mnew;
      char* pwB = (char*)p_s[w];
      #pragma unroll
      for (int mt = 0; mt < 4; ++mt) {
        uint2 uu;
        uu.x = cvt_pk_bf16(p[mt * 4 + 0], p[mt * 4 + 1]);
        uu.y = cvt_pk_bf16(p[mt * 4 + 2], p[mt * 4 + 3]);
        *(uint2*)(pwB + lo * 128 + ((mt * 32 + g * 8) ^ SWZK(lo))) = uu;
      }
      MCLOB;
      const float f0 = __shfl(f, 4 * g + 0), f1 = __shfl(f, 4 * g + 1);
      const float f2v = __shfl(f, 4 * g + 2), f3 = __shfl(f, 4 * g + 3);
      f32x4 fv; fv[0] = f0; fv[1] = f1; fv[2] = f2v; fv[3] = f3;
      #pragma unroll
      for (int d = 0; d < 4; ++d) oa[d] *= fv;
      #pragma unroll
      for (int kt = 0; kt < 2; ++kt) {
        short8 pa = *(const short8*)(pwB + lo * 128 + ((kt * 64 + g * 16) ^ SWZK(lo)));
        #pragma unroll
        for (int d = 0; d < 4; ++d) {
          const int r = d * 16 + lo;
          short8 vf = *(const short8*)((const char*)vT_s + r * 128 + ((kt * 64 + g * 16) ^ SWZV(r)));
          oa[d] = MFMA16(pa, vf, oa[d]);
        }
      }
    }
    AT_SB;
    __builtin_amdgcn_s_barrier();
    acur = (acur == 2) ? 0 : acur + 1;
  }
#undef ALSTAGE

  // epilogue: divide by row sums and store bf16
  const float l0 = __shfl(lrow, 4 * g + 0), l1 = __shfl(lrow, 4 * g + 1);
  const float l2 = __shfl(lrow, 4 * g + 2), l3 = __shfl(lrow, 4 * g + 3);
  const float iv[4] = {1.f / l0, 1.f / l1, 1.f / l2, 1.f / l3};
  u16* xrow = xb + (size_t)(b * 1024 + n0 + w * 16) * 1024 + h * 64;
  #pragma unroll
  for (int d = 0; d < 4; ++d)
    #pragma unroll
    for (int r = 0; r < 4; ++r)
      xrow[(size_t)(4 * g + r) * 1024 + d * 16 + lo] = f2bf(oa[d][r] * iv[r]);
}

extern "C" void kernel_launch(void* const* d_in, const int* in_sizes, int n_in,
                              void* d_out, int out_size, void* d_ws, size_t ws_size,
                              hipStream_t stream) {
  const float* q     = (const float*)d_in[0];   // [2,1024,1024]
  const float* kv    = (const float*)d_in[1];   // [2,2048,1024]
  const int*   pmask = (const int*)d_in[2];     // [2,2048] bool->int32
  const float* alibi = (const float*)d_in[3];   // [2,16,1024,2048]
  const float* Wq    = (const float*)d_in[4];   // [1024,1024]
  const float* Wkv   = (const float*)d_in[5];   // [2048,1024]
  const float* Wo    = (const float*)d_in[6];   // [1024,1024]
  const float* bo    = (const float*)d_in[7];   // [1024]
  const float* ls    = (const float*)d_in[8];   // [16]
  float* out = (float*)d_out;                   // [2,1024,1024]

  u16* ws = (u16*)d_ws;
  u16* q_bf   = ws;
  u16* kv_bf  = ws + (size_t)2  * 1024 * 1024;
  u16* Wq_bf  = ws + (size_t)6  * 1024 * 1024;
  u16* Wkv_bf = ws + (size_t)7  * 1024 * 1024;
  u16* Wo_bf  = ws + (size_t)9  * 1024 * 1024;
  u16* qh_bf  = ws + (size_t)10 * 1024 * 1024;  // [2048][1024] normalized*scale
  u16* kvp_bf = ws + (size_t)12 * 1024 * 1024;  // [4096][2048] k normalized | v
  u16* xb     = ws + (size_t)20 * 1024 * 1024;  // [2048][1024]
  u32* mbits  = (u32*)(ws + (size_t)22 * 1024 * 1024);  // [2][64]

  cast_all<<<5121, 256, 0, stream>>>(q, kv, Wq, Wkv, Wo, pmask,
                                     q_bf, kv_bf, Wq_bf, Wkv_bf, Wo_bf, mbits);

  proj_fused<<<640, 256, 0, stream>>>(q_bf, kv_bf, Wq_bf, Wkv_bf, ls, qh_bf, kvp_bf);

  attn_mfma<<<512, 256, 0, stream>>>(qh_bf, kvp_bf, alibi, mbits, xb);

  gemm_out<<<256, 256, 0, stream>>>(xb, Wo_bf, bo, out);
}

// Round 14
// 158.722 us; speedup vs baseline: 3.9852x; 1.0959x over previous
//
#include <hip/hip_runtime.h>
#include <hip/hip_bf16.h>
#include <math.h>

typedef unsigned short u16;
typedef unsigned int u32;
using f32x4 = __attribute__((ext_vector_type(4))) float;
using short8 = __attribute__((ext_vector_type(8))) short;

#define LOGIT_MAX 4.605170185988091f
#define MFMA16(a,b,c) __builtin_amdgcn_mfma_f32_16x16x32_bf16((a),(b),(c),0,0,0)
// LDS XOR swizzles for 128B rows (m214: byte ^= ((row&7)<<4))
#define SWZK(r) ((((r)&7))<<4)
#define SWZV(r) (((((r)^((r)>>3))&7))<<4)
#define MCLOB asm volatile("" ::: "memory")

__device__ __forceinline__ u16 f2bf(float f) {
  u32 u = __float_as_uint(f);
  return (u16)((u + 0x7FFFu + ((u >> 16) & 1u)) >> 16);  // RNE
}
__device__ __forceinline__ u32 cvt_pk_bf16(float a, float b) {  // low=bf16(a), high=bf16(b)
  u32 r;
  asm("v_cvt_pk_bf16_f32 %0, %1, %2" : "=v"(r) : "v"(a), "v"(b));
  return r;
}
__device__ __forceinline__ void gload16(const void* g, void* l) {
  __builtin_amdgcn_global_load_lds(
      (const __attribute__((address_space(1))) u32*)g,
      (__attribute__((address_space(3))) u32*)l, 16, 0, 0);
}

// ------- fused f32->bf16 casts (5 regions) + padding-mask->bitmask -------
__global__ __launch_bounds__(256) void cast_all(
    const float* __restrict__ q, const float* __restrict__ kv,
    const float* __restrict__ Wq, const float* __restrict__ Wkv,
    const float* __restrict__ Wo, const int* __restrict__ pm,
    u16* __restrict__ qb, u16* __restrict__ kvb, u16* __restrict__ wqb,
    u16* __restrict__ wkvb, u16* __restrict__ wob, u32* __restrict__ mbits) {
  const int bid = blockIdx.x, t = threadIdx.x;
  if (bid == 5120) {  // mask -> bits: [2][2048] int -> [2][64] u32
    if (t < 128) {
      u32 bits = 0;
      const int* mp = pm + (t >> 6) * 2048 + (t & 63) * 32;
      #pragma unroll
      for (int j = 0; j < 32; ++j) bits |= (mp[j] ? 1u : 0u) << j;
      mbits[t] = bits;
    }
    return;
  }
  const float* s; u16* d; int base;
  if (bid < 1024)      { s = q;   d = qb;   base = bid; }
  else if (bid < 3072) { s = kv;  d = kvb;  base = bid - 1024; }
  else if (bid < 3584) { s = Wq;  d = wqb;  base = bid - 3072; }
  else if (bid < 4608) { s = Wkv; d = wkvb; base = bid - 3584; }
  else                 { s = Wo;  d = wob;  base = bid - 4608; }
  const size_t i = ((size_t)base * 256 + t) * 8;
  float4 a = *(const float4*)(s + i);
  float4 b = *(const float4*)(s + i + 4);
  short8 v;
  v[0] = (short)f2bf(a.x); v[1] = (short)f2bf(a.y);
  v[2] = (short)f2bf(a.z); v[3] = (short)f2bf(a.w);
  v[4] = (short)f2bf(b.x); v[5] = (short)f2bf(b.y);
  v[6] = (short)f2bf(b.z); v[7] = (short)f2bf(b.w);
  *(short8*)(d + i) = v;
}

// ------------- GEMM NT bf16 body: C[M,N] = A[M,K] * B[N,K]^T -------------
// BM/BN tile; 4 waves. (128,128): 2x2 waves of 64x64. (64,64): stacked 16x64.
// 2-phase counted-vmcnt pipeline.
// NORM: 0=none, 1=l2norm 64-col head segs when col<1024 (k), 2=l2norm+scale (q)
template<int BM, int BN, int NORM, bool BIAS, bool BF16OUT>
__device__ __forceinline__ void gemm_body(
    const u16* __restrict__ A, const u16* __restrict__ B,
    const float* __restrict__ bias, const float* __restrict__ ls,
    void* __restrict__ Cv, int M, int N, int K, int bx, int by,
    u16* a_s, u16* b_s)   // a_s[2][BM*32], b_s[2][BN*32]
{
  constexpr int MT = (BN == 128) ? 4 : (BM == 128 ? 2 : 1);
  constexpr int ASTR = BM * 32;
  constexpr int BSTR = BN * 32;
  const int t = threadIdx.x, w = t >> 6, l = t & 63, lo = l & 15, g = (l >> 4) & 3;
  const int row0 = by * BM, col0 = bx * BN;
  const int wr = (BN == 128) ? ((w >> 1) * 64) : (BM == 128 ? w * 32 : w * 16);
  const int wc = (BN == 128) ? ((w & 1) * 64) : 0;
  f32x4 acc[MT][4];
  #pragma unroll
  for (int i = 0; i < MT; ++i)
    #pragma unroll
    for (int j = 0; j < 4; ++j) { acc[i][j][0]=0.f; acc[i][j][1]=0.f; acc[i][j][2]=0.f; acc[i][j][3]=0.f; }

  const int sr = l >> 2, sc = (l & 3) * 8;
  const u16* Ag;
  u16* adst;
  if (BM == 128) { Ag = A + (size_t)(row0 + w * 32 + sr) * K + sc; adst = a_s + w * 1024; }
  else           { Ag = A + (size_t)(row0 + w * 16 + sr) * K + sc; adst = a_s + w * 512; }
  const u16* Bg;
  u16* bdst;
  if (BN == 128) { Bg = B + (size_t)(col0 + w * 32 + sr) * K + sc; bdst = b_s + w * 1024; }
  else           { Bg = B + (size_t)(col0 + w * 16 + sr) * K + sc; bdst = b_s + w * 512; }

  auto STAGE = [&](int kt, int pb) {
    const int k0 = kt * 32;
    gload16(Ag + k0, adst + pb * ASTR);
    if (BM == 128) gload16(Ag + (size_t)16 * K + k0, adst + pb * ASTR + 512);
    gload16(Bg + k0, bdst + pb * BSTR);
    if (BN == 128) gload16(Bg + (size_t)16 * K + k0, bdst + pb * BSTR + 512);
  };

  const int NKT = K >> 5;
  STAGE(0, 0);
  for (int kt = 0; kt < NKT; ++kt) {
    const int cb = kt & 1;
    if (kt + 1 < NKT) {
      STAGE(kt + 1, cb ^ 1);
      MCLOB;
      if constexpr (BM == 128 && BN == 128)      asm volatile("s_waitcnt vmcnt(4)" ::: "memory");
      else if constexpr (BM == 128 || BN == 128) asm volatile("s_waitcnt vmcnt(3)" ::: "memory");
      else                                       asm volatile("s_waitcnt vmcnt(2)" ::: "memory");
    } else {
      asm volatile("s_waitcnt vmcnt(0)" ::: "memory");
    }
    __builtin_amdgcn_s_barrier();
    MCLOB;
    const u16* ab = a_s + cb * ASTR;
    const u16* bb = b_s + cb * BSTR;
    short8 af[MT], bfr[4];
    #pragma unroll
    for (int mt = 0; mt < MT; ++mt) af[mt] = *(const short8*)&ab[(wr + mt * 16 + lo) * 32 + g * 8];
    #pragma unroll
    for (int nt = 0; nt < 4; ++nt) bfr[nt] = *(const short8*)&bb[(wc + nt * 16 + lo) * 32 + g * 8];
    #pragma unroll
    for (int mt = 0; mt < MT; ++mt)
      #pragma unroll
      for (int nt = 0; nt < 4; ++nt)
        acc[mt][nt] = MFMA16(af[mt], bfr[nt], acc[mt][nt]);
    MCLOB;
    __builtin_amdgcn_s_barrier();
  }
  if (NORM == 2 || (NORM == 1 && col0 < 1024)) {
    float scl = 1.f;
    if (NORM == 2) scl = __expf(fminf(ls[(col0 + wc) >> 6], LOGIT_MAX));
    #pragma unroll
    for (int mt = 0; mt < MT; ++mt)
      #pragma unroll
      for (int r = 0; r < 4; ++r) {
        float s = 0.f;
        #pragma unroll
        for (int nt = 0; nt < 4; ++nt) s = fmaf(acc[mt][nt][r], acc[mt][nt][r], s);
        s += __shfl_xor(s, 1); s += __shfl_xor(s, 2);
        s += __shfl_xor(s, 4); s += __shfl_xor(s, 8);
        float inv = scl / fmaxf(sqrtf(s), 1e-12f);
        #pragma unroll
        for (int nt = 0; nt < 4; ++nt) acc[mt][nt][r] *= inv;
      }
  }
  #pragma unroll
  for (int mt = 0; mt < MT; ++mt) {
    const int rrow = row0 + wr + mt * 16 + g * 4;
    #pragma unroll
    for (int nt = 0; nt < 4; ++nt) {
      const int ccol = col0 + wc + nt * 16 + lo;
      const float bv = BIAS ? bias[ccol] : 0.f;
      #pragma unroll
      for (int r = 0; r < 4; ++r) {
        const float v = acc[mt][nt][r] + bv;
        if (BF16OUT) ((u16*)Cv)[(size_t)(rrow + r) * N + ccol] = f2bf(v);
        else         ((float*)Cv)[(size_t)(rrow + r) * N + ccol] = v;
      }
    }
  }
}

// projections: blocks [0,512)=kvp 128x128; [512,1024)=q-proj 64x64
__global__ __launch_bounds__(256) void proj_fused(
    const u16* __restrict__ q_bf, const u16* __restrict__ kv_bf,
    const u16* __restrict__ Wq_bf, const u16* __restrict__ Wkv_bf,
    const float* __restrict__ ls, u16* __restrict__ qh, u16* __restrict__ kvp) {
  __shared__ __align__(16) u16 a_s[2 * 4096];
  __shared__ __align__(16) u16 b_s[2 * 4096];
  const int bid = blockIdx.x;
  if (bid < 512)
    gemm_body<128, 128, 1, false, true>(kv_bf, Wkv_bf, nullptr, nullptr, kvp,
                                        4096, 2048, 1024, bid & 15, bid >> 4, a_s, b_s);
  else
    gemm_body<64, 64, 2, false, true>(q_bf, Wq_bf, nullptr, ls, qh,
                                      2048, 1024, 1024, (bid - 512) & 15, (bid - 512) >> 4, a_s, b_s);
}

__global__ __launch_bounds__(256) void gemm_out(
    const u16* __restrict__ xb, const u16* __restrict__ Wo_bf,
    const float* __restrict__ bo, float* __restrict__ out) {
  __shared__ __align__(16) u16 a_s[2 * 2048];
  __shared__ __align__(16) u16 b_s[2 * 2048];
  gemm_body<64, 64, 0, true, false>(xb, Wo_bf, bo, nullptr, out,
                                    2048, 1024, 1024, blockIdx.x & 15, blockIdx.x >> 4, a_s, b_s);
}

// ---------------- Flash attention, bf16 MFMA, QBLK=64, KVBLK=64, 4 waves ----------------
// R7's replay-validated structure, verbatim (no non-temporal loads): alibi in
// registers, fetched in 4-tile groups (16 float4/lane, 1KB-contiguous per row),
// issued one group ahead mid-compute; K via gload_lds dbuf; V reg->LDS transposed.
__global__ __launch_bounds__(256) void attn_mfma(
    const u16* __restrict__ qn, const u16* __restrict__ kvp,
    const float* __restrict__ alibi, const u32* __restrict__ mbits,
    u16* __restrict__ xb)
{
  __shared__ __align__(16) u16 k_s[2][64 * 64];
  __shared__ __align__(16) u16 vT_s[2][64 * 64];
  __shared__ __align__(16) u16 p_s[4][16 * 64];
  const int t = threadIdx.x, w = t >> 6, l = t & 63, lo = l & 15, g = (l >> 4) & 3;
  const int bid = blockIdx.x;
  const int bh = bid & 31, b = bh >> 4, h = bh & 15;   // same-(b,h) blocks share an XCD
  const int n0 = (bid >> 5) * 64;

  const u16* qrow = qn + (size_t)(b * 1024 + n0 + w * 16 + lo) * 1024 + h * 64;
  const short8 qf0 = *(const short8*)(qrow + g * 8);
  const short8 qf1 = *(const short8*)(qrow + 32 + g * 8);

  const u16* kbase = kvp + (size_t)(b * 2048) * 2048 + h * 64;
  const u16* vbase = kbase + 1024;
  const float* albase = alibi + ((size_t)(bh * 1024 + n0 + w * 16 + lo)) * 2048;

  const int kr0 = w * 16 + (l >> 3);
  const int kcolb = (l & 7) * 16;
  const int vdq = (t & 7) * 8;        // d0 of this thread's V micro-tile
  const int vmp = (t >> 3) * 2;       // m (even) of this thread's V micro-tile

  float mrow = -1e30f, lrow = 0.f;
  f32x4 oa[4];
  #pragma unroll
  for (int d = 0; d < 4; ++d) { oa[d][0]=0.f; oa[d][1]=0.f; oa[d][2]=0.f; oa[d][3]=0.f; }

  float4 alr[16];      // 4 tiles x 4 mt, literal-indexed only (rule #20)
  short8 va, vb;

#define ALOAD(G) {                                                                  \
    const float* abp = albase + (size_t)(G) * 256;                                  \
    _Pragma("unroll")                                                               \
    for (int jj = 0; jj < 16; ++jj)                                                 \
      alr[jj] = *(const float4*)(abp + (jj >> 2) * 64 + (jj & 3) * 16 + g * 4);     \
  }

  // ---- prologue: mask word, alibi group 0, K(0), V(0) (VMEM order pinned) ----
  const u32 mword = mbits[b * 64 + l];
  ALOAD(0);
  MCLOB;
  gload16((const char*)kbase + (size_t)kr0 * 4096 + (kcolb ^ SWZK(kr0)), (char*)k_s[0] + w * 2048);
  gload16((const char*)kbase + (size_t)(kr0 + 8) * 4096 + (kcolb ^ SWZK(kr0 + 8)), (char*)k_s[0] + w * 2048 + 1024);
  MCLOB;
  {
    const u16* v0p = vbase + (size_t)vmp * 2048 + vdq;
    va = *(const short8*)v0p;
    vb = *(const short8*)(v0p + 2048);
  }
  MCLOB;

  // BODY: [waitv (outside)] V-write | K/V(t+1) issue | lgkm+barrier | compute(t)
  //       (incl. next alibi-group issue at J==3) | barrier
#define BODY(J, CB, TI) {                                                           \
    { char* vdst = (char*)vT_s[CB];                                                 \
      _Pragma("unroll")                                                             \
      for (int j = 0; j < 8; ++j) {                                                 \
        u32 pk = (u32)(u16)va[j] | ((u32)(u16)vb[j] << 16);                         \
        int r = vdq + j;                                                            \
        *(u32*)(vdst + r * 128 + ((vmp * 2) ^ SWZV(r))) = pk; } }                   \
    MCLOB;                                                                          \
    if ((TI) < 31) {                                                                \
      const int m1 = ((TI) + 1) * 64;                                               \
      gload16((const char*)kbase + (size_t)(m1 + kr0) * 4096 + (kcolb ^ SWZK(kr0)), \
              (char*)k_s[(CB) ^ 1] + w * 2048);                                     \
      gload16((const char*)kbase + (size_t)(m1 + kr0 + 8) * 4096 + (kcolb ^ SWZK(kr0 + 8)), \
              (char*)k_s[(CB) ^ 1] + w * 2048 + 1024);                              \
      MCLOB;                                                                        \
      const u16* v1p = vbase + (size_t)(m1 + vmp) * 2048 + vdq;                     \
      va = *(const short8*)v1p;                                                     \
      vb = *(const short8*)(v1p + 2048);                                            \
    }                                                                               \
    asm volatile("s_waitcnt lgkmcnt(0)" ::: "memory");                              \
    __builtin_amdgcn_s_barrier();                                                   \
    MCLOB;                                                                          \
    /* ---- compute tile TI ---- */                                                 \
    {                                                                               \
      f32x4 st[4];                                                                  \
      _Pragma("unroll")                                                             \
      for (int mt = 0; mt < 4; ++mt) {                                              \
        const int r = mt * 16 + lo;                                                 \
        const char* krow = (const char*)k_s[CB] + r * 128;                          \
        short8 ka0 = *(const short8*)(krow + ((g * 16) ^ SWZK(r)));                 \
        short8 ka1 = *(const short8*)(krow + ((64 + g * 16) ^ SWZK(r)));            \
        f32x4 z; z[0]=0.f; z[1]=0.f; z[2]=0.f; z[3]=0.f;                            \
        st[mt] = MFMA16(ka0, qf0, z);                                               \
        st[mt] = MFMA16(ka1, qf1, st[mt]);                                          \
      }                                                                             \
      const u32 cw0 = __shfl(mword, (TI) * 2), cw1 = __shfl(mword, (TI) * 2 + 1);   \
      float p[16]; float pmax = -1e30f;                                             \
      _Pragma("unroll")                                                             \
      for (int mt = 0; mt < 4; ++mt) {                                              \
        const float4 A4 = alr[(J) * 4 + mt];                                        \
        const float aa[4] = {A4.x, A4.y, A4.z, A4.w};                               \
        const u32 wsel = (mt >= 2) ? cw1 : cw0;                                     \
        _Pragma("unroll")                                                           \
        for (int r = 0; r < 4; ++r) {                                               \
          const int idx = mt * 16 + g * 4 + r;                                      \
          const float v = ((wsel >> (idx & 31)) & 1u) ? -1e30f : (st[mt][r] + aa[r]); \
          p[mt * 4 + r] = v;                                                        \
          pmax = fmaxf(pmax, v);                                                    \
        }                                                                           \
      }                                                                             \
      pmax = fmaxf(pmax, __shfl_xor(pmax, 16));                                     \
      pmax = fmaxf(pmax, __shfl_xor(pmax, 32));                                     \
      const float mnew = fmaxf(mrow, pmax);                                         \
      const float f = __expf(mrow - mnew);                                          \
      float sum = 0.f;                                                              \
      _Pragma("unroll")                                                             \
      for (int i = 0; i < 16; ++i) { p[i] = __expf(p[i] - mnew); sum += p[i]; }     \
      sum += __shfl_xor(sum, 16);                                                   \
      sum += __shfl_xor(sum, 32);                                                   \
      lrow = lrow * f + sum;                                                        \
      mrow = mnew;                                                                  \
      if ((J) == 3 && g4 < 7) ALOAD(g4 + 1);    /* next alibi group, 1KB/row burst */ \
      char* pwB = (char*)p_s[w];                                                    \
      _Pragma("unroll")                                                             \
      for (int mt = 0; mt < 4; ++mt) {                                              \
        uint2 uu;                                                                   \
        uu.x = cvt_pk_bf16(p[mt * 4 + 0], p[mt * 4 + 1]);                           \
        uu.y = cvt_pk_bf16(p[mt * 4 + 2], p[mt * 4 + 3]);                           \
        *(uint2*)(pwB + lo * 128 + ((mt * 32 + g * 8) ^ SWZK(lo))) = uu;            \
      }                                                                             \
      asm volatile("" ::: "memory");                                                \
      const float f0 = __shfl(f, 4 * g + 0), f1 = __shfl(f, 4 * g + 1);             \
      const float f2v = __shfl(f, 4 * g + 2), f3 = __shfl(f, 4 * g + 3);            \
      f32x4 fv; fv[0] = f0; fv[1] = f1; fv[2] = f2v; fv[3] = f3;                    \
      _Pragma("unroll")                                                             \
      for (int d = 0; d < 4; ++d) oa[d] *= fv;                                      \
      _Pragma("unroll")                                                             \
      for (int kt = 0; kt < 2; ++kt) {                                              \
        short8 pa = *(const short8*)(pwB + lo * 128 + ((kt * 64 + g * 16) ^ SWZK(lo))); \
        _Pragma("unroll")                                                           \
        for (int d = 0; d < 4; ++d) {                                               \
          const int r = d * 16 + lo;                                                \
          short8 vf = *(const short8*)((const char*)vT_s[CB] + r * 128 + ((kt * 64 + g * 16) ^ SWZV(r))); \
          oa[d] = MFMA16(pa, vf, oa[d]);                                            \
        }                                                                           \
      }                                                                             \
    }                                                                               \
    MCLOB;                                                                          \
    __builtin_amdgcn_s_barrier();                                                   \
  }

  for (int g4 = 0; g4 < 8; ++g4) {
    const int t0 = g4 * 4;
    // j=0: outstanding after K(t) = V(t)2 + [alibi group 16 if g4>=1]
    if (g4 == 0) asm volatile("s_waitcnt vmcnt(2)" ::: "memory");
    else         asm volatile("s_waitcnt vmcnt(18)" ::: "memory");
    BODY(0, 0, t0 + 0);
    asm volatile("s_waitcnt vmcnt(2)" ::: "memory");
    BODY(1, 1, t0 + 1);
    asm volatile("s_waitcnt vmcnt(2)" ::: "memory");
    BODY(2, 0, t0 + 2);
    asm volatile("s_waitcnt vmcnt(2)" ::: "memory");
    BODY(3, 1, t0 + 3);
  }
#undef BODY
#undef ALOAD

  // epilogue: divide by row sums and store bf16
  const float l0 = __shfl(lrow, 4 * g + 0), l1 = __shfl(lrow, 4 * g + 1);
  const float l2 = __shfl(lrow, 4 * g + 2), l3 = __shfl(lrow, 4 * g + 3);
  const float iv[4] = {1.f / l0, 1.f / l1, 1.f / l2, 1.f / l3};
  u16* xrow = xb + (size_t)(b * 1024 + n0 + w * 16) * 1024 + h * 64;
  #pragma unroll
  for (int d = 0; d < 4; ++d)
    #pragma unroll
    for (int r = 0; r < 4; ++r)
      xrow[(size_t)(4 * g + r) * 1024 + d * 16 + lo] = f2bf(oa[d][r] * iv[r]);
}

extern "C" void kernel_launch(void* const* d_in, const int* in_sizes, int n_in,
                              void* d_out, int out_size, void* d_ws, size_t ws_size,
                              hipStream_t stream) {
  const float* q     = (const float*)d_in[0];   // [2,1024,1024]
  const float* kv    = (const float*)d_in[1];   // [2,2048,1024]
  const int*   pmask = (const int*)d_in[2];     // [2,2048] bool->int32
  const float* alibi = (const float*)d_in[3];   // [2,16,1024,2048]
  const float* Wq    = (const float*)d_in[4];   // [1024,1024]
  const float* Wkv   = (const float*)d_in[5];   // [2048,1024]
  const float* Wo    = (const float*)d_in[6];   // [1024,1024]
  const float* bo    = (const float*)d_in[7];   // [1024]
  const float* ls    = (const float*)d_in[8];   // [16]
  float* out = (float*)d_out;                   // [2,1024,1024]

  u16* ws = (u16*)d_ws;
  u16* q_bf   = ws;
  u16* kv_bf  = ws + (size_t)2  * 1024 * 1024;
  u16* Wq_bf  = ws + (size_t)6  * 1024 * 1024;
  u16* Wkv_bf = ws + (size_t)7  * 1024 * 1024;
  u16* Wo_bf  = ws + (size_t)9  * 1024 * 1024;
  u16* qh_bf  = ws + (size_t)10 * 1024 * 1024;  // [2048][1024] normalized*scale
  u16* kvp_bf = ws + (size_t)12 * 1024 * 1024;  // [4096][2048] k normalized | v
  u16* xb     = ws + (size_t)20 * 1024 * 1024;  // [2048][1024]
  u32* mbits  = (u32*)(ws + (size_t)22 * 1024 * 1024);  // [2][64]

  cast_all<<<5121, 256, 0, stream>>>(q, kv, Wq, Wkv, Wo, pmask,
                                     q_bf, kv_bf, Wq_bf, Wkv_bf, Wo_bf, mbits);

  proj_fused<<<1024, 256, 0, stream>>>(q_bf, kv_bf, Wq_bf, Wkv_bf, ls, qh_bf, kvp_bf);

  attn_mfma<<<512, 256, 0, stream>>>(qh_bf, kvp_bf, alibi, mbits, xb);

  gemm_out<<<512, 256, 0, stream>>>(xb, Wo_bf, bo, out);
}

// Round 16
// 158.350 us; speedup vs baseline: 3.9946x; 1.0023x over previous
//
#include <hip/hip_runtime.h>
#include <hip/hip_bf16.h>
#include <math.h>

typedef unsigned short u16;
typedef unsigned int u32;
using f32x4 = __attribute__((ext_vector_type(4))) float;
using short8 = __attribute__((ext_vector_type(8))) short;

#define LOGIT_MAX 4.605170185988091f
#define MFMA16(a,b,c) __builtin_amdgcn_mfma_f32_16x16x32_bf16((a),(b),(c),0,0,0)
// LDS XOR swizzles for 128B rows (m214: byte ^= ((row&7)<<4))
#define SWZK(r) ((((r)&7))<<4)
#define SWZV(r) (((((r)^((r)>>3))&7))<<4)
#define MCLOB asm volatile("" ::: "memory")

__device__ __forceinline__ u16 f2bf(float f) {
  u32 u = __float_as_uint(f);
  return (u16)((u + 0x7FFFu + ((u >> 16) & 1u)) >> 16);  // RNE
}
__device__ __forceinline__ u32 cvt_pk_bf16(float a, float b) {  // low=bf16(a), high=bf16(b)
  u32 r;
  asm("v_cvt_pk_bf16_f32 %0, %1, %2" : "=v"(r) : "v"(a), "v"(b));
  return r;
}
__device__ __forceinline__ void gload16(const void* g, void* l) {
  __builtin_amdgcn_global_load_lds(
      (const __attribute__((address_space(1))) u32*)g,
      (__attribute__((address_space(3))) u32*)l, 16, 0, 0);
}

// ------- fused f32->bf16 casts (5 regions) + padding-mask->bitmask -------
__global__ __launch_bounds__(256) void cast_all(
    const float* __restrict__ q, const float* __restrict__ kv,
    const float* __restrict__ Wq, const float* __restrict__ Wkv,
    const float* __restrict__ Wo, const int* __restrict__ pm,
    u16* __restrict__ qb, u16* __restrict__ kvb, u16* __restrict__ wqb,
    u16* __restrict__ wkvb, u16* __restrict__ wob, u32* __restrict__ mbits) {
  const int bid = blockIdx.x, t = threadIdx.x;
  if (bid == 5120) {  // mask -> bits: [2][2048] int -> [2][64] u32
    if (t < 128) {
      u32 bits = 0;
      const int* mp = pm + (t >> 6) * 2048 + (t & 63) * 32;
      #pragma unroll
      for (int j = 0; j < 32; ++j) bits |= (mp[j] ? 1u : 0u) << j;
      mbits[t] = bits;
    }
    return;
  }
  const float* s; u16* d; int base;
  if (bid < 1024)      { s = q;   d = qb;   base = bid; }
  else if (bid < 3072) { s = kv;  d = kvb;  base = bid - 1024; }
  else if (bid < 3584) { s = Wq;  d = wqb;  base = bid - 3072; }
  else if (bid < 4608) { s = Wkv; d = wkvb; base = bid - 3584; }
  else                 { s = Wo;  d = wob;  base = bid - 4608; }
  const size_t i = ((size_t)base * 256 + t) * 8;
  float4 a = *(const float4*)(s + i);
  float4 b = *(const float4*)(s + i + 4);
  short8 v;
  v[0] = (short)f2bf(a.x); v[1] = (short)f2bf(a.y);
  v[2] = (short)f2bf(a.z); v[3] = (short)f2bf(a.w);
  v[4] = (short)f2bf(b.x); v[5] = (short)f2bf(b.y);
  v[6] = (short)f2bf(b.z); v[7] = (short)f2bf(b.w);
  *(short8*)(d + i) = v;
}

// ------------- GEMM NT bf16 body: C[M,N] = A[M,K] * B[N,K]^T -------------
// BM/BN tile; 4 waves. (128,128): 2x2 waves of 64x64. (64,64): stacked 16x64.
// 2-phase counted-vmcnt pipeline.
// NORM: 0=none, 1=l2norm 64-col head segs when col<1024 (k), 2=l2norm+scale (q)
template<int BM, int BN, int NORM, bool BIAS, bool BF16OUT>
__device__ __forceinline__ void gemm_body(
    const u16* __restrict__ A, const u16* __restrict__ B,
    const float* __restrict__ bias, const float* __restrict__ ls,
    void* __restrict__ Cv, int M, int N, int K, int bx, int by,
    u16* a_s, u16* b_s)   // a_s[2][BM*32], b_s[2][BN*32]
{
  constexpr int MT = (BN == 128) ? 4 : (BM == 128 ? 2 : 1);
  constexpr int ASTR = BM * 32;
  constexpr int BSTR = BN * 32;
  const int t = threadIdx.x, w = t >> 6, l = t & 63, lo = l & 15, g = (l >> 4) & 3;
  const int row0 = by * BM, col0 = bx * BN;
  const int wr = (BN == 128) ? ((w >> 1) * 64) : (BM == 128 ? w * 32 : w * 16);
  const int wc = (BN == 128) ? ((w & 1) * 64) : 0;
  f32x4 acc[MT][4];
  #pragma unroll
  for (int i = 0; i < MT; ++i)
    #pragma unroll
    for (int j = 0; j < 4; ++j) { acc[i][j][0]=0.f; acc[i][j][1]=0.f; acc[i][j][2]=0.f; acc[i][j][3]=0.f; }

  const int sr = l >> 2, sc = (l & 3) * 8;
  const u16* Ag;
  u16* adst;
  if (BM == 128) { Ag = A + (size_t)(row0 + w * 32 + sr) * K + sc; adst = a_s + w * 1024; }
  else           { Ag = A + (size_t)(row0 + w * 16 + sr) * K + sc; adst = a_s + w * 512; }
  const u16* Bg;
  u16* bdst;
  if (BN == 128) { Bg = B + (size_t)(col0 + w * 32 + sr) * K + sc; bdst = b_s + w * 1024; }
  else           { Bg = B + (size_t)(col0 + w * 16 + sr) * K + sc; bdst = b_s + w * 512; }

  auto STAGE = [&](int kt, int pb) {
    const int k0 = kt * 32;
    gload16(Ag + k0, adst + pb * ASTR);
    if (BM == 128) gload16(Ag + (size_t)16 * K + k0, adst + pb * ASTR + 512);
    gload16(Bg + k0, bdst + pb * BSTR);
    if (BN == 128) gload16(Bg + (size_t)16 * K + k0, bdst + pb * BSTR + 512);
  };

  const int NKT = K >> 5;
  STAGE(0, 0);
  for (int kt = 0; kt < NKT; ++kt) {
    const int cb = kt & 1;
    if (kt + 1 < NKT) {
      STAGE(kt + 1, cb ^ 1);
      MCLOB;
      if constexpr (BM == 128 && BN == 128)      asm volatile("s_waitcnt vmcnt(4)" ::: "memory");
      else if constexpr (BM == 128 || BN == 128) asm volatile("s_waitcnt vmcnt(3)" ::: "memory");
      else                                       asm volatile("s_waitcnt vmcnt(2)" ::: "memory");
    } else {
      asm volatile("s_waitcnt vmcnt(0)" ::: "memory");
    }
    __builtin_amdgcn_s_barrier();
    MCLOB;
    const u16* ab = a_s + cb * ASTR;
    const u16* bb = b_s + cb * BSTR;
    short8 af[MT], bfr[4];
    #pragma unroll
    for (int mt = 0; mt < MT; ++mt) af[mt] = *(const short8*)&ab[(wr + mt * 16 + lo) * 32 + g * 8];
    #pragma unroll
    for (int nt = 0; nt < 4; ++nt) bfr[nt] = *(const short8*)&bb[(wc + nt * 16 + lo) * 32 + g * 8];
    #pragma unroll
    for (int mt = 0; mt < MT; ++mt)
      #pragma unroll
      for (int nt = 0; nt < 4; ++nt)
        acc[mt][nt] = MFMA16(af[mt], bfr[nt], acc[mt][nt]);
    MCLOB;
    __builtin_amdgcn_s_barrier();
  }
  if (NORM == 2 || (NORM == 1 && col0 < 1024)) {
    float scl = 1.f;
    if (NORM == 2) scl = __expf(fminf(ls[(col0 + wc) >> 6], LOGIT_MAX));
    #pragma unroll
    for (int mt = 0; mt < MT; ++mt)
      #pragma unroll
      for (int r = 0; r < 4; ++r) {
        float s = 0.f;
        #pragma unroll
        for (int nt = 0; nt < 4; ++nt) s = fmaf(acc[mt][nt][r], acc[mt][nt][r], s);
        s += __shfl_xor(s, 1); s += __shfl_xor(s, 2);
        s += __shfl_xor(s, 4); s += __shfl_xor(s, 8);
        float inv = scl / fmaxf(sqrtf(s), 1e-12f);
        #pragma unroll
        for (int nt = 0; nt < 4; ++nt) acc[mt][nt][r] *= inv;
      }
  }
  #pragma unroll
  for (int mt = 0; mt < MT; ++mt) {
    const int rrow = row0 + wr + mt * 16 + g * 4;
    #pragma unroll
    for (int nt = 0; nt < 4; ++nt) {
      const int ccol = col0 + wc + nt * 16 + lo;
      const float bv = BIAS ? bias[ccol] : 0.f;
      #pragma unroll
      for (int r = 0; r < 4; ++r) {
        const float v = acc[mt][nt][r] + bv;
        if (BF16OUT) ((u16*)Cv)[(size_t)(rrow + r) * N + ccol] = f2bf(v);
        else         ((float*)Cv)[(size_t)(rrow + r) * N + ccol] = v;
      }
    }
  }
}

// projections: blocks [0,512)=kvp 128x128; [512,1024)=q-proj 64x64
__global__ __launch_bounds__(256) void proj_fused(
    const u16* __restrict__ q_bf, const u16* __restrict__ kv_bf,
    const u16* __restrict__ Wq_bf, const u16* __restrict__ Wkv_bf,
    const float* __restrict__ ls, u16* __restrict__ qh, u16* __restrict__ kvp) {
  __shared__ __align__(16) u16 a_s[2 * 4096];
  __shared__ __align__(16) u16 b_s[2 * 4096];
  const int bid = blockIdx.x;
  if (bid < 512)
    gemm_body<128, 128, 1, false, true>(kv_bf, Wkv_bf, nullptr, nullptr, kvp,
                                        4096, 2048, 1024, bid & 15, bid >> 4, a_s, b_s);
  else
    gemm_body<64, 64, 2, false, true>(q_bf, Wq_bf, nullptr, ls, qh,
                                      2048, 1024, 1024, (bid - 512) & 15, (bid - 512) >> 4, a_s, b_s);
}

__global__ __launch_bounds__(256) void gemm_out(
    const u16* __restrict__ xb, const u16* __restrict__ Wo_bf,
    const float* __restrict__ bo, float* __restrict__ out) {
  __shared__ __align__(16) u16 a_s[2 * 2048];
  __shared__ __align__(16) u16 b_s[2 * 2048];
  gemm_body<64, 64, 0, true, false>(xb, Wo_bf, bo, nullptr, out,
                                    2048, 1024, 1024, blockIdx.x & 15, blockIdx.x >> 4, a_s, b_s);
}

// ---------------- Flash attention, bf16 MFMA, QBLK=64, KVBLK=64, 4 waves ----------------
// R7's replay-validated structure, verbatim (no non-temporal loads): alibi in
// registers, fetched in 4-tile groups (16 float4/lane, 1KB-contiguous per row),
// issued one group ahead mid-compute; K via gload_lds dbuf; V reg->LDS transposed.
__global__ __launch_bounds__(256) void attn_mfma(
    const u16* __restrict__ qn, const u16* __restrict__ kvp,
    const float* __restrict__ alibi, const u32* __restrict__ mbits,
    u16* __restrict__ xb)
{
  __shared__ __align__(16) u16 k_s[2][64 * 64];
  __shared__ __align__(16) u16 vT_s[2][64 * 64];
  __shared__ __align__(16) u16 p_s[4][16 * 64];
  const int t = threadIdx.x, w = t >> 6, l = t & 63, lo = l & 15, g = (l >> 4) & 3;
  const int bid = blockIdx.x;
  const int bh = bid & 31, b = bh >> 4, h = bh & 15;   // same-(b,h) blocks share an XCD
  const int n0 = (bid >> 5) * 64;

  const u16* qrow = qn + (size_t)(b * 1024 + n0 + w * 16 + lo) * 1024 + h * 64;
  const short8 qf0 = *(const short8*)(qrow + g * 8);
  const short8 qf1 = *(const short8*)(qrow + 32 + g * 8);

  const u16* kbase = kvp + (size_t)(b * 2048) * 2048 + h * 64;
  const u16* vbase = kbase + 1024;
  const float* albase = alibi + ((size_t)(bh * 1024 + n0 + w * 16 + lo)) * 2048;

  const int kr0 = w * 16 + (l >> 3);
  const int kcolb = (l & 7) * 16;
  const int vdq = (t & 7) * 8;        // d0 of this thread's V micro-tile
  const int vmp = (t >> 3) * 2;       // m (even) of this thread's V micro-tile

  float mrow = -1e30f, lrow = 0.f;
  f32x4 oa[4];
  #pragma unroll
  for (int d = 0; d < 4; ++d) { oa[d][0]=0.f; oa[d][1]=0.f; oa[d][2]=0.f; oa[d][3]=0.f; }

  float4 alr[16];      // 4 tiles x 4 mt, literal-indexed only (rule #20)
  short8 va, vb;

#define ALOAD(G) {                                                                  \
    const float* abp = albase + (size_t)(G) * 256;                                  \
    _Pragma("unroll")                                                               \
    for (int jj = 0; jj < 16; ++jj)                                                 \
      alr[jj] = *(const float4*)(abp + (jj >> 2) * 64 + (jj & 3) * 16 + g * 4);     \
  }

  // ---- prologue: mask word, alibi group 0, K(0), V(0) (VMEM order pinned) ----
  const u32 mword = mbits[b * 64 + l];
  ALOAD(0);
  MCLOB;
  gload16((const char*)kbase + (size_t)kr0 * 4096 + (kcolb ^ SWZK(kr0)), (char*)k_s[0] + w * 2048);
  gload16((const char*)kbase + (size_t)(kr0 + 8) * 4096 + (kcolb ^ SWZK(kr0 + 8)), (char*)k_s[0] + w * 2048 + 1024);
  MCLOB;
  {
    const u16* v0p = vbase + (size_t)vmp * 2048 + vdq;
    va = *(const short8*)v0p;
    vb = *(const short8*)(v0p + 2048);
  }
  MCLOB;

  // BODY: [waitv (outside)] V-write | K/V(t+1) issue | lgkm+barrier | compute(t)
  //       (incl. next alibi-group issue at J==3) | barrier
#define BODY(J, CB, TI) {                                                           \
    { char* vdst = (char*)vT_s[CB];                                                 \
      _Pragma("unroll")                                                             \
      for (int j = 0; j < 8; ++j) {                                                 \
        u32 pk = (u32)(u16)va[j] | ((u32)(u16)vb[j] << 16);                         \
        int r = vdq + j;                                                            \
        *(u32*)(vdst + r * 128 + ((vmp * 2) ^ SWZV(r))) = pk; } }                   \
    MCLOB;                                                                          \
    if ((TI) < 31) {                                                                \
      const int m1 = ((TI) + 1) * 64;                                               \
      gload16((const char*)kbase + (size_t)(m1 + kr0) * 4096 + (kcolb ^ SWZK(kr0)), \
              (char*)k_s[(CB) ^ 1] + w * 2048);                                     \
      gload16((const char*)kbase + (size_t)(m1 + kr0 + 8) * 4096 + (kcolb ^ SWZK(kr0 + 8)), \
              (char*)k_s[(CB) ^ 1] + w * 2048 + 1024);                              \
      MCLOB;                                                                        \
      const u16* v1p = vbase + (size_t)(m1 + vmp) * 2048 + vdq;                     \
      va = *(const short8*)v1p;                                                     \
      vb = *(const short8*)(v1p + 2048);                                            \
    }                                                                               \
    asm volatile("s_waitcnt lgkmcnt(0)" ::: "memory");                              \
    __builtin_amdgcn_s_barrier();                                                   \
    MCLOB;                                                                          \
    /* ---- compute tile TI ---- */                                                 \
    {                                                                               \
      f32x4 st[4];                                                                  \
      _Pragma("unroll")                                                             \
      for (int mt = 0; mt < 4; ++mt) {                                              \
        const int r = mt * 16 + lo;                                                 \
        const char* krow = (const char*)k_s[CB] + r * 128;                          \
        short8 ka0 = *(const short8*)(krow + ((g * 16) ^ SWZK(r)));                 \
        short8 ka1 = *(const short8*)(krow + ((64 + g * 16) ^ SWZK(r)));            \
        f32x4 z; z[0]=0.f; z[1]=0.f; z[2]=0.f; z[3]=0.f;                            \
        st[mt] = MFMA16(ka0, qf0, z);                                               \
        st[mt] = MFMA16(ka1, qf1, st[mt]);                                          \
      }                                                                             \
      const u32 cw0 = __shfl(mword, (TI) * 2), cw1 = __shfl(mword, (TI) * 2 + 1);   \
      float p[16]; float pmax = -1e30f;                                             \
      _Pragma("unroll")                                                             \
      for (int mt = 0; mt < 4; ++mt) {                                              \
        const float4 A4 = alr[(J) * 4 + mt];                                        \
        const float aa[4] = {A4.x, A4.y, A4.z, A4.w};                               \
        const u32 wsel = (mt >= 2) ? cw1 : cw0;                                     \
        _Pragma("unroll")                                                           \
        for (int r = 0; r < 4; ++r) {                                               \
          const int idx = mt * 16 + g * 4 + r;                                      \
          const float v = ((wsel >> (idx & 31)) & 1u) ? -1e30f : (st[mt][r] + aa[r]); \
          p[mt * 4 + r] = v;                                                        \
          pmax = fmaxf(pmax, v);                                                    \
        }                                                                           \
      }                                                                             \
      pmax = fmaxf(pmax, __shfl_xor(pmax, 16));                                     \
      pmax = fmaxf(pmax, __shfl_xor(pmax, 32));                                     \
      const float mnew = fmaxf(mrow, pmax);                                         \
      const float f = __expf(mrow - mnew);                                          \
      float sum = 0.f;                                                              \
      _Pragma("unroll")                                                             \
      for (int i = 0; i < 16; ++i) { p[i] = __expf(p[i] - mnew); sum += p[i]; }     \
      sum += __shfl_xor(sum, 16);                                                   \
      sum += __shfl_xor(sum, 32);                                                   \
      lrow = lrow * f + sum;                                                        \
      mrow = mnew;                                                                  \
      if ((J) == 3 && g4 < 7) ALOAD(g4 + 1);    /* next alibi group, 1KB/row burst */ \
      char* pwB = (char*)p_s[w];                                                    \
      _Pragma("unroll")                                                             \
      for (int mt = 0; mt < 4; ++mt) {                                              \
        uint2 uu;                                                                   \
        uu.x = cvt_pk_bf16(p[mt * 4 + 0], p[mt * 4 + 1]);                           \
        uu.y = cvt_pk_bf16(p[mt * 4 + 2], p[mt * 4 + 3]);                           \
        *(uint2*)(pwB + lo * 128 + ((mt * 32 + g * 8) ^ SWZK(lo))) = uu;            \
      }                                                                             \
      asm volatile("" ::: "memory");                                                \
      const float f0 = __shfl(f, 4 * g + 0), f1 = __shfl(f, 4 * g + 1);             \
      const float f2v = __shfl(f, 4 * g + 2), f3 = __shfl(f, 4 * g + 3);            \
      f32x4 fv; fv[0] = f0; fv[1] = f1; fv[2] = f2v; fv[3] = f3;                    \
      _Pragma("unroll")                                                             \
      for (int d = 0; d < 4; ++d) oa[d] *= fv;                                      \
      _Pragma("unroll")                                                             \
      for (int kt = 0; kt < 2; ++kt) {                                              \
        short8 pa = *(const short8*)(pwB + lo * 128 + ((kt * 64 + g * 16) ^ SWZK(lo))); \
        _Pragma("unroll")                                                           \
        for (int d = 0; d < 4; ++d) {                                               \
          const int r = d * 16 + lo;                                                \
          short8 vf = *(const short8*)((const char*)vT_s[CB] + r * 128 + ((kt * 64 + g * 16) ^ SWZV(r))); \
          oa[d] = MFMA16(pa, vf, oa[d]);                                            \
        }                                                                           \
      }                                                                             \
    }                                                                               \
    MCLOB;                                                                          \
    __builtin_amdgcn_s_barrier();                                                   \
  }

  for (int g4 = 0; g4 < 8; ++g4) {
    const int t0 = g4 * 4;
    // j=0: outstanding after K(t) = V(t)2 + [alibi group 16 if g4>=1]
    if (g4 == 0) asm volatile("s_waitcnt vmcnt(2)" ::: "memory");
    else         asm volatile("s_waitcnt vmcnt(18)" ::: "memory");
    BODY(0, 0, t0 + 0);
    asm volatile("s_waitcnt vmcnt(2)" ::: "memory");
    BODY(1, 1, t0 + 1);
    asm volatile("s_waitcnt vmcnt(2)" ::: "memory");
    BODY(2, 0, t0 + 2);
    asm volatile("s_waitcnt vmcnt(2)" ::: "memory");
    BODY(3, 1, t0 + 3);
  }
#undef BODY
#undef ALOAD

  // epilogue: divide by row sums and store bf16
  const float l0 = __shfl(lrow, 4 * g + 0), l1 = __shfl(lrow, 4 * g + 1);
  const float l2 = __shfl(lrow, 4 * g + 2), l3 = __shfl(lrow, 4 * g + 3);
  const float iv[4] = {1.f / l0, 1.f / l1, 1.f / l2, 1.f / l3};
  u16* xrow = xb + (size_t)(b * 1024 + n0 + w * 16) * 1024 + h * 64;
  #pragma unroll
  for (int d = 0; d < 4; ++d)
    #pragma unroll
    for (int r = 0; r < 4; ++r)
      xrow[(size_t)(4 * g + r) * 1024 + d * 16 + lo] = f2bf(oa[d][r] * iv[r]);
}

extern "C" void kernel_launch(void* const* d_in, const int* in_sizes, int n_in,
                              void* d_out, int out_size, void* d_ws, size_t ws_size,
                              hipStream_t stream) {
  const float* q     = (const float*)d_in[0];   // [2,1024,1024]
  const float* kv    = (const float*)d_in[1];   // [2,2048,1024]
  const int*   pmask = (const int*)d_in[2];     // [2,2048] bool->int32
  const float* alibi = (const float*)d_in[3];   // [2,16,1024,2048]
  const float* Wq    = (const float*)d_in[4];   // [1024,1024]
  const float* Wkv   = (const float*)d_in[5];   // [2048,1024]
  const float* Wo    = (const float*)d_in[6];   // [1024,1024]
  const float* bo    = (const float*)d_in[7];   // [1024]
  const float* ls    = (const float*)d_in[8];   // [16]
  float* out = (float*)d_out;                   // [2,1024,1024]

  u16* ws = (u16*)d_ws;
  u16* q_bf   = ws;
  u16* kv_bf  = ws + (size_t)2  * 1024 * 1024;
  u16* Wq_bf  = ws + (size_t)6  * 1024 * 1024;
  u16* Wkv_bf = ws + (size_t)7  * 1024 * 1024;
  u16* Wo_bf  = ws + (size_t)9  * 1024 * 1024;
  u16* qh_bf  = ws + (size_t)10 * 1024 * 1024;  // [2048][1024] normalized*scale
  u16* kvp_bf = ws + (size_t)12 * 1024 * 1024;  // [4096][2048] k normalized | v
  u16* xb     = ws + (size_t)20 * 1024 * 1024;  // [2048][1024]
  u32* mbits  = (u32*)(ws + (size_t)22 * 1024 * 1024);  // [2][64]

  cast_all<<<5121, 256, 0, stream>>>(q, kv, Wq, Wkv, Wo, pmask,
                                     q_bf, kv_bf, Wq_bf, Wkv_bf, Wo_bf, mbits);

  proj_fused<<<1024, 256, 0, stream>>>(q_bf, kv_bf, Wq_bf, Wkv_bf, ls, qh_bf, kvp_bf);

  attn_mfma<<<512, 256, 0, stream>>>(qh_bf, kvp_bf, alibi, mbits, xb);

  gemm_out<<<512, 256, 0, stream>>>(xb, Wo_bf, bo, out);
}